// Round 1
// baseline (783.884 us; speedup 1.0000x reference)
//
#include <hip/hip_runtime.h>

#define T_DIM 8192
#define H_DIM 1024
#define E_NUM 64
#define I_DIM 512
#define K_TOP 6
#define CAP   1536
#define SCALE 2.5f

typedef __attribute__((ext_vector_type(8))) short short8;
typedef __attribute__((ext_vector_type(4))) float floatx4;

__device__ __forceinline__ unsigned short f2bf(float f) {
    unsigned u = __float_as_uint(f);
    u += 0x7FFF + ((u >> 16) & 1);          // round-to-nearest-even
    return (unsigned short)(u >> 16);
}
__device__ __forceinline__ float bf2f(unsigned short h) {
    return __uint_as_float(((unsigned)h) << 16);
}

// ---------------------------------------------------------------------------
// 1) Router logits: logits[T,64] = x[T,1024] @ gate_w[1024,64]  (fp32 exact-ish)
// ---------------------------------------------------------------------------
__global__ __launch_bounds__(256) void router_logits_kernel(
    const float* __restrict__ x, const float* __restrict__ gw,
    float* __restrict__ logits) {
    __shared__ float xs[64][68];
    __shared__ float wsh[64][68];
    const int t0  = blockIdx.x * 64;
    const int tid = threadIdx.x;
    const int rr  = tid >> 4;            // 0..15
    const int c4  = (tid & 15) * 4;      // 0..60
    const int ty  = tid >> 4, tx = tid & 15;

    float acc[4][4];
#pragma unroll
    for (int j = 0; j < 4; j++)
#pragma unroll
        for (int l = 0; l < 4; l++) acc[j][l] = 0.f;

    for (int h0 = 0; h0 < H_DIM; h0 += 64) {
#pragma unroll
        for (int i = 0; i < 4; i++) {
            int r = rr + i * 16;
            float4 v = *(const float4*)(x + (size_t)(t0 + r) * H_DIM + h0 + c4);
            xs[r][c4 + 0] = v.x; xs[r][c4 + 1] = v.y; xs[r][c4 + 2] = v.z; xs[r][c4 + 3] = v.w;
            float4 w = *(const float4*)(gw + (size_t)(h0 + r) * E_NUM + c4);
            wsh[r][c4 + 0] = w.x; wsh[r][c4 + 1] = w.y; wsh[r][c4 + 2] = w.z; wsh[r][c4 + 3] = w.w;
        }
        __syncthreads();
#pragma unroll 8
        for (int kh = 0; kh < 64; kh++) {
            float a0 = xs[ty * 4 + 0][kh], a1 = xs[ty * 4 + 1][kh];
            float a2 = xs[ty * 4 + 2][kh], a3 = xs[ty * 4 + 3][kh];
            float b0 = wsh[kh][tx * 4 + 0], b1 = wsh[kh][tx * 4 + 1];
            float b2 = wsh[kh][tx * 4 + 2], b3 = wsh[kh][tx * 4 + 3];
            acc[0][0] += a0 * b0; acc[0][1] += a0 * b1; acc[0][2] += a0 * b2; acc[0][3] += a0 * b3;
            acc[1][0] += a1 * b0; acc[1][1] += a1 * b1; acc[1][2] += a1 * b2; acc[1][3] += a1 * b3;
            acc[2][0] += a2 * b0; acc[2][1] += a2 * b1; acc[2][2] += a2 * b2; acc[2][3] += a2 * b3;
            acc[3][0] += a3 * b0; acc[3][1] += a3 * b1; acc[3][2] += a3 * b2; acc[3][3] += a3 * b3;
        }
        __syncthreads();
    }
#pragma unroll
    for (int j = 0; j < 4; j++)
#pragma unroll
        for (int l = 0; l < 4; l++)
            logits[(size_t)(t0 + ty * 4 + j) * E_NUM + tx * 4 + l] = acc[j][l];
}

// ---------------------------------------------------------------------------
// 2) Grouped sigmoid top-k routing + atomic dispatch.  One thread per token.
// ---------------------------------------------------------------------------
__global__ __launch_bounds__(64) void route_kernel(
    const float* __restrict__ logits, const float* __restrict__ bias,
    int* __restrict__ ids, float* __restrict__ wts, int* __restrict__ poss,
    int* __restrict__ cnt, int* __restrict__ tlist) {
    __shared__ float sc[64][65];   // [expert][thread] -> no cross-thread sharing
    const int tid = threadIdx.x;
    const int t = blockIdx.x * 64 + tid;
    const float* lrow = logits + (size_t)t * E_NUM;

#pragma unroll
    for (int e = 0; e < 64; e++) {
        float s = 1.0f / (1.0f + expf(-lrow[e]));
        sc[e][tid] = s + bias[e];
    }
    // group scores = sum of top-2 corrected scores per group of 8
    float gs[8];
#pragma unroll
    for (int g = 0; g < 8; g++) {
        float m1 = -1e30f, m2 = -1e30f;
#pragma unroll
        for (int i = 0; i < 8; i++) {
            float v = sc[g * 8 + i][tid];
            if (v > m1) { m2 = m1; m1 = v; } else if (v > m2) { m2 = v; }
        }
        gs[g] = m1 + m2;
    }
    // top-4 groups (strict > keeps lowest index on ties, matching lax.top_k)
    unsigned gm = 0;
    for (int k = 0; k < 4; k++) {
        float best = -1e30f; int bi = 0;
#pragma unroll
        for (int g = 0; g < 8; g++) {
            bool ok = !((gm >> g) & 1);
            if (ok && gs[g] > best) { best = gs[g]; bi = g; }
        }
        gm |= 1u << bi;
    }
    // top-6 experts among allowed groups
    unsigned long long taken = 0;
    int   idk[K_TOP];
    float wk[K_TOP];
    float wsum = 0.f;
    for (int k = 0; k < K_TOP; k++) {
        float best = -1e30f; int bi = 0;
#pragma unroll
        for (int e = 0; e < 64; e++) {
            bool allow = ((gm >> (e >> 3)) & 1) && !((taken >> e) & 1);
            float v = sc[e][tid];
            if (allow && v > best) { best = v; bi = e; }
        }
        taken |= 1ull << bi;
        idk[k] = bi;
        float s = 1.0f / (1.0f + expf(-lrow[bi]));   // weight from RAW sigmoid
        wk[k] = s; wsum += s;
    }
    float inv = 1.0f / wsum;
#pragma unroll
    for (int k = 0; k < K_TOP; k++) {
        int e = idk[k];
        ids[(size_t)t * K_TOP + k] = e;
        wts[(size_t)t * K_TOP + k] = wk[k] * inv;
        int p = atomicAdd(&cnt[e], 1);
        if (p < CAP) { tlist[e * CAP + p] = t; poss[(size_t)t * K_TOP + k] = p; }
        else         { poss[(size_t)t * K_TOP + k] = -1; }
    }
}

// ---------------------------------------------------------------------------
// 3) Exclusive scan of per-expert counts -> packed row bases
// ---------------------------------------------------------------------------
__global__ void scan_kernel(const int* __restrict__ cnt, int* __restrict__ base) {
    if (threadIdx.x == 0 && blockIdx.x == 0) {
        int s = 0;
        for (int e = 0; e < E_NUM; e++) {
            base[e] = s;
            int c = cnt[e]; if (c > CAP) c = CAP;
            s += c;
        }
    }
}

// ---------------------------------------------------------------------------
// 4) x fp32 -> bf16
// ---------------------------------------------------------------------------
__global__ __launch_bounds__(256) void cvt_x_kernel(
    const float* __restrict__ x, unsigned short* __restrict__ xb) {
    size_t i = ((size_t)blockIdx.x * 256 + threadIdx.x) * 4;
    float4 v = *(const float4*)(x + i);
    ushort4 o;
    o.x = f2bf(v.x); o.y = f2bf(v.y); o.z = f2bf(v.z); o.w = f2bf(v.w);
    *(ushort4*)(xb + i) = o;
}

// ---------------------------------------------------------------------------
// 5) Batched transpose + convert: src [B][R][C] fp32 -> dst [B][C][R] bf16
// ---------------------------------------------------------------------------
__global__ __launch_bounds__(256) void transpose_kernel(
    const float* __restrict__ src, unsigned short* __restrict__ dst, int R, int C) {
    const int b = blockIdx.z;
    src += (size_t)b * R * C;
    dst += (size_t)b * R * C;
    const int r0 = blockIdx.y * 64, c0 = blockIdx.x * 64;
    __shared__ unsigned short tbuf[64][68];
    const int tid = threadIdx.x;
    const int rr = tid >> 4, c4 = (tid & 15) * 4;
#pragma unroll
    for (int i = 0; i < 4; i++) {
        int r = rr + i * 16;
        float4 v = *(const float4*)(src + (size_t)(r0 + r) * C + c0 + c4);
        tbuf[r][c4 + 0] = f2bf(v.x); tbuf[r][c4 + 1] = f2bf(v.y);
        tbuf[r][c4 + 2] = f2bf(v.z); tbuf[r][c4 + 3] = f2bf(v.w);
    }
    __syncthreads();
#pragma unroll
    for (int i = 0; i < 4; i++) {
        int ci = rr + i * 16;
        ushort4 o;
        o.x = tbuf[c4 + 0][ci]; o.y = tbuf[c4 + 1][ci];
        o.z = tbuf[c4 + 2][ci]; o.w = tbuf[c4 + 3][ci];
        *(ushort4*)(dst + (size_t)(c0 + ci) * R + r0 + c4) = o;
    }
}

// ---------------------------------------------------------------------------
// 6) MFMA GEMM, 128x128 tile, BK=64, 4 waves of 4x4 16x16x32 frags.
//    A [M,K] bf16 (optionally gathered rows via tlist), B [N,K] bf16 (pre-T),
//    C row-major [.,N]: bf16 (+optional relu^2) or fp32.
// ---------------------------------------------------------------------------
template <bool GATHER, bool RELU2, bool OUTF32>
__global__ __launch_bounds__(256, 2) void gemm_kernel(
    const unsigned short* __restrict__ A, const unsigned short* __restrict__ B,
    void* __restrict__ Cout,
    const int* __restrict__ cnt, const int* __restrict__ basep,
    const int* __restrict__ tlist,
    int N, int K, int fixedM) {
    const int e = blockIdx.z;
    const int M = cnt ? min(cnt[e], CAP) : fixedM;
    const int m0 = blockIdx.y * 128;
    if (m0 >= M) return;
    const int n0 = blockIdx.x * 128;
    const int rowbase = basep ? basep[e] : 0;
    const unsigned short* Be = B + (size_t)e * N * K;

    __shared__ __align__(16) unsigned short a_s[128 * 72];
    __shared__ __align__(16) unsigned short b_s[128 * 72];

    const int tid  = threadIdx.x;
    const int srow = tid >> 1;          // 0..127
    const int sseg = (tid & 1) * 32;    // elem offset within 64-elem row

    const int gr = m0 + srow;
    const bool av = gr < M;
    const unsigned short* arow;
    if (GATHER) {
        int t = av ? tlist[e * CAP + gr] : 0;
        arow = A + (size_t)t * K;
    } else {
        arow = A + (size_t)(rowbase + (av ? gr : 0)) * K;
    }
    const unsigned short* brow = Be + (size_t)(n0 + srow) * K;

    const int w = tid >> 6, lane = tid & 63;
    const int wm = (w >> 1) * 64, wn = (w & 1) * 64;
    const int lm = lane & 15, q = lane >> 4;

    floatx4 acc[4][4];
#pragma unroll
    for (int a = 0; a < 4; a++)
#pragma unroll
        for (int b2 = 0; b2 < 4; b2++) acc[a][b2] = (floatx4){0.f, 0.f, 0.f, 0.f};

    for (int k0 = 0; k0 < K; k0 += 64) {
        // ---- stage A/B tiles ----
        {
            uint4* as = (uint4*)&a_s[srow * 72 + sseg];
            if (av) {
                const uint4* ap = (const uint4*)(arow + k0 + sseg);
                uint4 x0 = ap[0], x1 = ap[1], x2 = ap[2], x3 = ap[3];
                as[0] = x0; as[1] = x1; as[2] = x2; as[3] = x3;
            } else {
                uint4 z = {0u, 0u, 0u, 0u};
                as[0] = z; as[1] = z; as[2] = z; as[3] = z;
            }
            const uint4* bp = (const uint4*)(brow + k0 + sseg);
            uint4 y0 = bp[0], y1 = bp[1], y2 = bp[2], y3 = bp[3];
            uint4* bs = (uint4*)&b_s[srow * 72 + sseg];
            bs[0] = y0; bs[1] = y1; bs[2] = y2; bs[3] = y3;
        }
        __syncthreads();
        // ---- MFMA ----
#pragma unroll
        for (int kk = 0; kk < 2; kk++) {
            short8 af[4], bf[4];
#pragma unroll
            for (int i = 0; i < 4; i++) {
                af[i] = *(const short8*)&a_s[(wm + i * 16 + lm) * 72 + kk * 32 + q * 8];
                bf[i] = *(const short8*)&b_s[(wn + i * 16 + lm) * 72 + kk * 32 + q * 8];
            }
#pragma unroll
            for (int mi = 0; mi < 4; mi++)
#pragma unroll
                for (int ni = 0; ni < 4; ni++)
                    acc[mi][ni] = __builtin_amdgcn_mfma_f32_16x16x32_bf16(
                        af[mi], bf[ni], acc[mi][ni], 0, 0, 0);
        }
        __syncthreads();
    }

    // ---- epilogue ----
#pragma unroll
    for (int mi = 0; mi < 4; mi++) {
#pragma unroll
        for (int i = 0; i < 4; i++) {
            int r = wm + mi * 16 + q * 4 + i;
            if (m0 + r < M) {
                size_t Rrow = (size_t)(rowbase + m0 + r);
#pragma unroll
                for (int ni = 0; ni < 4; ni++) {
                    float v = acc[mi][ni][i];
                    if (RELU2) { v = v > 0.f ? v * v : 0.f; }
                    int c = n0 + wn + ni * 16 + lm;
                    if (OUTF32) ((float*)Cout)[Rrow * N + c] = v;
                    else        ((unsigned short*)Cout)[Rrow * N + c] = f2bf(v);
                }
            }
        }
    }
}

// ---------------------------------------------------------------------------
// 7) Combine: out[t] += SCALE * sum_k w[t,k] * Y[base[id]+pos]   (one block/token)
// ---------------------------------------------------------------------------
__global__ __launch_bounds__(256) void combine_kernel(
    const unsigned short* __restrict__ Y, const int* __restrict__ ids,
    const float* __restrict__ wts, const int* __restrict__ poss,
    const int* __restrict__ base, float* __restrict__ out) {
    __shared__ int   s_slot[K_TOP];
    __shared__ float s_w[K_TOP];
    const int t = blockIdx.x, tid = threadIdx.x;
    if (tid < K_TOP) {
        int id = ids[(size_t)t * K_TOP + tid];
        int p  = poss[(size_t)t * K_TOP + tid];
        s_slot[tid] = (p >= 0) ? (base[id] + p) : -1;
        s_w[tid]    = wts[(size_t)t * K_TOP + tid];
    }
    __syncthreads();
    const int c = tid * 4;
    float a0 = 0.f, a1 = 0.f, a2 = 0.f, a3 = 0.f;
#pragma unroll
    for (int k = 0; k < K_TOP; k++) {
        int slot = s_slot[k];
        if (slot >= 0) {
            float wkk = s_w[k];
            ushort4 y = *(const ushort4*)(Y + (size_t)slot * H_DIM + c);
            a0 += wkk * bf2f(y.x); a1 += wkk * bf2f(y.y);
            a2 += wkk * bf2f(y.z); a3 += wkk * bf2f(y.w);
        }
    }
    float4 o = *(float4*)(out + (size_t)t * H_DIM + c);
    o.x += SCALE * a0; o.y += SCALE * a1; o.z += SCALE * a2; o.w += SCALE * a3;
    *(float4*)(out + (size_t)t * H_DIM + c) = o;
}

// ---------------------------------------------------------------------------
extern "C" void kernel_launch(void* const* d_in, const int* in_sizes, int n_in,
                              void* d_out, int out_size, void* d_ws, size_t ws_size,
                              hipStream_t stream) {
    const float* x         = (const float*)d_in[0];
    const float* gate_w    = (const float*)d_in[1];
    const float* gate_bias = (const float*)d_in[2];
    const float* w_up      = (const float*)d_in[3];
    const float* w_down    = (const float*)d_in[4];
    const float* sh_up     = (const float*)d_in[5];
    const float* sh_down   = (const float*)d_in[6];
    float* out = (float*)d_out;

    char* ws = (char*)d_ws;
    size_t off = 0;
    auto alloc = [&](size_t b) { size_t o = off; off += (b + 255) & ~(size_t)255; return o; };
    float*          logits = (float*)(ws + alloc((size_t)T_DIM * E_NUM * 4));
    int*            ids    = (int*)  (ws + alloc((size_t)T_DIM * K_TOP * 4));
    float*          wts    = (float*)(ws + alloc((size_t)T_DIM * K_TOP * 4));
    int*            poss   = (int*)  (ws + alloc((size_t)T_DIM * K_TOP * 4));
    int*            cnt    = (int*)  (ws + alloc(256));
    int*            base   = (int*)  (ws + alloc(256));
    int*            tlist  = (int*)  (ws + alloc((size_t)E_NUM * CAP * 4));
    unsigned short* xb     = (unsigned short*)(ws + alloc((size_t)T_DIM * H_DIM * 2));
    unsigned short* wupT   = (unsigned short*)(ws + alloc((size_t)E_NUM * H_DIM * I_DIM * 2));
    unsigned short* wdnT   = (unsigned short*)(ws + alloc((size_t)E_NUM * H_DIM * I_DIM * 2));
    unsigned short* shupT  = (unsigned short*)(ws + alloc((size_t)H_DIM * H_DIM * 2));
    unsigned short* shdnT  = (unsigned short*)(ws + alloc((size_t)H_DIM * H_DIM * 2));
    unsigned short* hact   = (unsigned short*)(ws + alloc((size_t)T_DIM * K_TOP * I_DIM * 2));
    unsigned short* Ybuf   = (unsigned short*)(ws + alloc((size_t)T_DIM * K_TOP * H_DIM * 2));
    unsigned short* smid   = (unsigned short*)(ws + alloc((size_t)T_DIM * H_DIM * 2));

    hipMemsetAsync(cnt, 0, 256, stream);

    router_logits_kernel<<<dim3(T_DIM / 64), 256, 0, stream>>>(x, gate_w, logits);
    route_kernel<<<dim3(T_DIM / 64), 64, 0, stream>>>(logits, gate_bias, ids, wts, poss, cnt, tlist);
    scan_kernel<<<1, 64, 0, stream>>>(cnt, base);
    cvt_x_kernel<<<dim3((T_DIM * H_DIM / 4) / 256), 256, 0, stream>>>(x, xb);
    // w_up [E][H][I] -> wupT [E][I][H]
    transpose_kernel<<<dim3(I_DIM / 64, H_DIM / 64, E_NUM), 256, 0, stream>>>(w_up, wupT, H_DIM, I_DIM);
    // w_down [E][I][H] -> wdnT [E][H][I]
    transpose_kernel<<<dim3(H_DIM / 64, I_DIM / 64, E_NUM), 256, 0, stream>>>(w_down, wdnT, I_DIM, H_DIM);
    transpose_kernel<<<dim3(H_DIM / 64, H_DIM / 64, 1), 256, 0, stream>>>(sh_up, shupT, H_DIM, H_DIM);
    transpose_kernel<<<dim3(H_DIM / 64, H_DIM / 64, 1), 256, 0, stream>>>(sh_down, shdnT, H_DIM, H_DIM);

    // expert up: gathered x @ w_upT -> relu^2 -> hact (packed rows)
    gemm_kernel<true, true, false><<<dim3(I_DIM / 128, CAP / 128, E_NUM), 256, 0, stream>>>(
        xb, wupT, hact, cnt, base, tlist, I_DIM, H_DIM, 0);
    // expert down: hact @ w_dnT -> Y (packed rows)
    gemm_kernel<false, false, false><<<dim3(H_DIM / 128, CAP / 128, E_NUM), 256, 0, stream>>>(
        hact, wdnT, Ybuf, cnt, base, nullptr, H_DIM, I_DIM, 0);
    // shared up: x @ shupT -> relu^2 -> smid
    gemm_kernel<false, true, false><<<dim3(H_DIM / 128, T_DIM / 128, 1), 256, 0, stream>>>(
        xb, shupT, smid, nullptr, nullptr, nullptr, H_DIM, H_DIM, T_DIM);
    // shared down: smid @ shdnT -> out (fp32, full overwrite)
    gemm_kernel<false, false, true><<<dim3(H_DIM / 128, T_DIM / 128, 1), 256, 0, stream>>>(
        smid, shdnT, out, nullptr, nullptr, nullptr, H_DIM, H_DIM, T_DIM);
    // combine routed experts onto shared output
    combine_kernel<<<dim3(T_DIM), 256, 0, stream>>>(Ybuf, ids, wts, poss, base, out);
    (void)in_sizes; (void)n_in; (void)out_size; (void)ws_size;
}